// Round 1
// baseline (293.809 us; speedup 1.0000x reference)
//
#include <hip/hip_runtime.h>
#include <hip/hip_bf16.h>

#define B_  128
#define T_  512
#define E_  12
#define H_  512
#define V_  16
#define DA_ 10
#define OUT_ 64
#define DH_ (2*H_)   // 1024

// ---------------------------------------------------------------------------
// K1: bidirectional QRNN scan. grid (B, 2dir), block 512 (one thread per h).
// Each thread holds its 36 weight cols + 3 biases in registers; the 12-dim
// encoder vector per t is staged in LDS (broadcast reads). Writes relu(o*c)
// to hbuf[b][t][dir*512+h].
// ---------------------------------------------------------------------------
template <typename ST>
__global__ __launch_bounds__(512) void qrnn_scan(
    const float* __restrict__ x,    // (B,T,3)
    const float* __restrict__ emb,  // (V,10)
    const float* __restrict__ Wf,   // (12,1536)
    const float* __restrict__ bf_,  // (1536)
    const float* __restrict__ Wb,   // (12,1536)
    const float* __restrict__ bb_,  // (1536)
    ST* __restrict__ hbuf)          // (B,T,1024)
{
    const int b   = blockIdx.x;
    const int dir = blockIdx.y;
    const int h   = threadIdx.x;
    const float* __restrict__ W    = dir ? Wb  : Wf;
    const float* __restrict__ bias = dir ? bb_ : bf_;

    __shared__ float enc[T_][E_];   // 24 KB, rows 48B (16B-aligned)

    // stage encoder: one thread per t
    {
        const int t = threadIdx.x;
        const float* xp = x + ((size_t)b * T_ + t) * 3;
        float ts0 = xp[0], ts1 = xp[1];
        int v = (int)xp[2];
        enc[t][0] = ts0;
        enc[t][1] = ts1;
        const float* ep = emb + v * DA_;
#pragma unroll
        for (int e = 0; e < DA_; ++e) enc[t][2 + e] = ep[e];
    }

    // per-thread weights
    float wz[E_], wf[E_], wo[E_];
#pragma unroll
    for (int e = 0; e < E_; ++e) {
        wz[e] = W[e * 1536 + h];
        wf[e] = W[e * 1536 + 512 + h];
        wo[e] = W[e * 1536 + 1024 + h];
    }
    const float bz = bias[h], bfv = bias[512 + h], bov = bias[1024 + h];

    __syncthreads();

    float c = 0.f;
    for (int step = 0; step < T_; ++step) {
        const int t = dir ? (T_ - 1 - step) : step;
        const float4* ep4 = (const float4*)enc[t];
        float4 e0 = ep4[0], e1 = ep4[1], e2 = ep4[2];
        float ev[E_] = {e0.x, e0.y, e0.z, e0.w,
                        e1.x, e1.y, e1.z, e1.w,
                        e2.x, e2.y, e2.z, e2.w};
        float zp = bz, fp = bfv, op = bov;
#pragma unroll
        for (int e = 0; e < E_; ++e) {
            zp = fmaf(ev[e], wz[e], zp);
            fp = fmaf(ev[e], wf[e], fp);
            op = fmaf(ev[e], wo[e], op);
        }
        const float f = 1.f / (1.f + __expf(-fp));
        const float o = 1.f / (1.f + __expf(-op));
        const float z = 2.f / (1.f + __expf(-2.f * zp)) - 1.f;  // tanh
        c = fmaf(f, c - z, z);
        const float hv = fmaxf(o * c, 0.f);
        hbuf[((size_t)b * T_ + t) * DH_ + dir * H_ + h] = (ST)hv;
    }
}

// ---------------------------------------------------------------------------
// K2: attention logits s[b,t] = dot(hbuf[b,t,:], Mu). One wave per row.
// ---------------------------------------------------------------------------
template <typename ST>
__global__ __launch_bounds__(256) void score_kernel(
    const ST* __restrict__ hbuf, const float* __restrict__ Mu,
    float* __restrict__ s)
{
    const int row  = blockIdx.x * 4 + (threadIdx.x >> 6);  // (b*T + t)
    const int lane = threadIdx.x & 63;
    const ST* hp = hbuf + (size_t)row * DH_;
    float acc = 0.f;
#pragma unroll
    for (int k = 0; k < DH_ / 64; ++k) {
        const int d = lane + k * 64;
        acc = fmaf((float)hp[d], Mu[d], acc);
    }
#pragma unroll
    for (int off = 32; off; off >>= 1) acc += __shfl_down(acc, off);
    if (lane == 0) s[row] = acc;
}

// ---------------------------------------------------------------------------
// K3: softmax over t per batch. grid B, block 512 (one thread per t).
// ---------------------------------------------------------------------------
__global__ __launch_bounds__(512) void softmax_kernel(
    const float* __restrict__ s, float* __restrict__ w)
{
    const int b = blockIdx.x;
    const int t = threadIdx.x;
    const float v = s[b * T_ + t];

    __shared__ float redm[8];
    __shared__ float reds[8];

    float m = v;
#pragma unroll
    for (int off = 32; off; off >>= 1) m = fmaxf(m, __shfl_xor(m, off));
    if ((t & 63) == 0) redm[t >> 6] = m;
    __syncthreads();
    float mall = redm[0];
#pragma unroll
    for (int i = 1; i < 8; ++i) mall = fmaxf(mall, redm[i]);

    const float e = __expf(v - mall);
    float sum = e;
#pragma unroll
    for (int off = 32; off; off >>= 1) sum += __shfl_xor(sum, off);
    if ((t & 63) == 0) reds[t >> 6] = sum;
    __syncthreads();
    float sall = 0.f;
#pragma unroll
    for (int i = 0; i < 8; ++i) sall += reds[i];

    w[b * T_ + t] = e / sall;
}

// ---------------------------------------------------------------------------
// K4: context[b,d] = relu( sum_t hbuf[b,t,d] * w[b,t] ). grid (B,4), block 256.
// ---------------------------------------------------------------------------
template <typename ST>
__global__ __launch_bounds__(256) void context_kernel(
    const ST* __restrict__ hbuf, const float* __restrict__ w,
    float* __restrict__ ctx)
{
    const int b = blockIdx.x;
    const int d = blockIdx.y * 256 + threadIdx.x;

    __shared__ float ws[T_];
    for (int t = threadIdx.x; t < T_; t += 256) ws[t] = w[b * T_ + t];
    __syncthreads();

    const ST* hp = hbuf + (size_t)b * T_ * DH_ + d;
    float acc = 0.f;
#pragma unroll 8
    for (int t = 0; t < T_; ++t)
        acc = fmaf((float)hp[(size_t)t * DH_], ws[t], acc);
    ctx[b * DH_ + d] = fmaxf(acc, 0.f);
}

// ---------------------------------------------------------------------------
// K5: out[b,o] = dot(ctx[b,:], W_out[o,:]) + b_out[o]. One wave per (b,o).
// ---------------------------------------------------------------------------
__global__ __launch_bounds__(256) void out_kernel(
    const float* __restrict__ ctx, const float* __restrict__ Wout,
    const float* __restrict__ bout, float* __restrict__ out)
{
    const int idx  = blockIdx.x * 4 + (threadIdx.x >> 6);  // b*64 + o
    const int lane = threadIdx.x & 63;
    const int b = idx >> 6;
    const int o = idx & 63;
    const float* cp = ctx + b * DH_;
    const float* wp = Wout + o * DH_;
    float acc = 0.f;
#pragma unroll
    for (int k = 0; k < DH_ / 64; ++k) {
        const int d = lane + k * 64;
        acc = fmaf(cp[d], wp[d], acc);
    }
#pragma unroll
    for (int off = 32; off; off >>= 1) acc += __shfl_down(acc, off);
    if (lane == 0) out[idx] = acc + bout[o];
}

// ---------------------------------------------------------------------------
template <typename ST>
static void run_pipeline(const float* x, const float* emb,
                         const float* Wf, const float* bf_,
                         const float* Wb, const float* bb_,
                         const float* Mu, const float* Wout, const float* bout,
                         float* out, char* ws, hipStream_t stream)
{
    const size_t hbytes = (size_t)B_ * T_ * DH_ * sizeof(ST);
    ST*    hbuf = (ST*)ws;
    float* s    = (float*)(ws + hbytes);
    float* w    = s + B_ * T_;
    float* ctx  = w + B_ * T_;

    qrnn_scan<ST><<<dim3(B_, 2), 512, 0, stream>>>(x, emb, Wf, bf_, Wb, bb_, hbuf);
    score_kernel<ST><<<(B_ * T_) / 4, 256, 0, stream>>>(hbuf, Mu, s);
    softmax_kernel<<<B_, 512, 0, stream>>>(s, w);
    context_kernel<ST><<<dim3(B_, DH_ / 256), 256, 0, stream>>>(hbuf, w, ctx);
    out_kernel<<<(B_ * OUT_) / 4, 256, 0, stream>>>(ctx, Wout, bout, out);
}

extern "C" void kernel_launch(void* const* d_in, const int* in_sizes, int n_in,
                              void* d_out, int out_size, void* d_ws, size_t ws_size,
                              hipStream_t stream)
{
    const float* x    = (const float*)d_in[0];
    const float* emb  = (const float*)d_in[1];
    const float* Wf   = (const float*)d_in[2];
    const float* bf_  = (const float*)d_in[3];
    const float* Wb   = (const float*)d_in[4];
    const float* bb_  = (const float*)d_in[5];
    const float* Mu   = (const float*)d_in[6];
    const float* Wout = (const float*)d_in[7];
    const float* bout = (const float*)d_in[8];
    float* out = (float*)d_out;

    const size_t tail = (size_t)B_ * T_ * sizeof(float) * 2 +
                        (size_t)B_ * DH_ * sizeof(float) + 4096;
    const size_t need_f32 = (size_t)B_ * T_ * DH_ * 4 + tail;

    if (ws_size >= need_f32) {
        run_pipeline<float>(x, emb, Wf, bf_, Wb, bb_, Mu, Wout, bout,
                            out, (char*)d_ws, stream);
    } else {
        run_pipeline<__hip_bfloat16>(x, emb, Wf, bf_, Wb, bb_, Mu, Wout, bout,
                                     out, (char*)d_ws, stream);
    }
}

// Round 2
// 209.717 us; speedup vs baseline: 1.4010x; 1.4010x over previous
//
#include <hip/hip_runtime.h>
#include <hip/hip_bf16.h>

typedef short short8 __attribute__((ext_vector_type(8)));

#define B_   128
#define T_   512
#define H_   512
#define V_   16
#define OUT_ 64
#define DH_  1024

// dynamic LDS for scan: tab float4[V][H] + tsq float4[T]
#define SCAN_LDS (V_*H_*16 + T_*16)   // 131072 + 8192 = 139264 B

__device__ __forceinline__ float bf2f(unsigned short u) {
    union { unsigned int i; float f; } x; x.i = ((unsigned int)u) << 16; return x.f;
}
__device__ __forceinline__ float sigm(float x) {
    return __builtin_amdgcn_rcpf(1.f + __expf(-x));   // v_rcp, not precise-div
}

// ---------------------------------------------------------------------------
// K1: bidirectional QRNN scan with per-(v,gate,h) precomputed table.
// grid (B,2), block 512 (thread = h). 1 block/CU.
// Per step: 2x ds_read_b128 (one broadcast) + 6 FMA + 3 sigmoid-family.
// ---------------------------------------------------------------------------
__global__ __launch_bounds__(512) void qrnn_scan2(
    const float* __restrict__ x,    // (B,T,3)
    const float* __restrict__ emb,  // (V,10)
    const float* __restrict__ Wf, const float* __restrict__ bf_,
    const float* __restrict__ Wb, const float* __restrict__ bb_,
    __hip_bfloat16* __restrict__ hbuf)  // (B,T,1024)
{
    const int b = blockIdx.x, dir = blockIdx.y, h = threadIdx.x;
    const float* __restrict__ W    = dir ? Wb  : Wf;
    const float* __restrict__ bias = dir ? bb_ : bf_;

    extern __shared__ char smem[];
    float4* tab = (float4*)smem;                 // [V][H]: (gz,gf,go,pad)
    float4* tsq = (float4*)(smem + V_*H_*16);    // [T]: (ts0,ts1,as_float(v),0)

    // stage x: one thread per t
    {
        const int t = h;
        const float* xp = x + ((size_t)b*T_ + t)*3;
        float t0 = xp[0], t1 = xp[1];
        int v = (int)xp[2];
        tsq[t] = make_float4(t0, t1, __int_as_float(v), 0.f);
    }

    // per-thread weight columns
    float w0[3], w1[3], wt[10][3];
#pragma unroll
    for (int g = 0; g < 3; ++g) {
        w0[g] = W[g*H_ + h];
        w1[g] = W[1536 + g*H_ + h];
#pragma unroll
        for (int e = 0; e < 10; ++e)
            wt[e][g] = W[(2+e)*1536 + g*H_ + h];
    }
    const float bz = bias[h], bfv = bias[H_+h], bov = bias[2*H_+h];

    // build gate table: tab[v] = bias + emb[v] . W[2:12]
#pragma unroll
    for (int v = 0; v < V_; ++v) {
        float a0 = bz, a1 = bfv, a2 = bov;
#pragma unroll
        for (int e = 0; e < 10; ++e) {
            const float ev = emb[v*10 + e];   // uniform -> scalar load
            a0 = fmaf(ev, wt[e][0], a0);
            a1 = fmaf(ev, wt[e][1], a1);
            a2 = fmaf(ev, wt[e][2], a2);
        }
        tab[v*H_ + h] = make_float4(a0, a1, a2, 0.f);
    }
    __syncthreads();

    float c = 0.f;
    __hip_bfloat16* hb = hbuf + ((size_t)b*T_ + (dir ? T_-1 : 0))*DH_ + dir*H_ + h;
    const ptrdiff_t stride = dir ? -(ptrdiff_t)DH_ : (ptrdiff_t)DH_;
    int t = dir ? T_-1 : 0;
    const int tstep = dir ? -1 : 1;

#pragma unroll 4
    for (int s = 0; s < T_; ++s) {
        const float4 q = tsq[t];              // broadcast b128
        const int v = __float_as_int(q.z);
        const float4 g = tab[v*H_ + h];       // b128, 16B/lane, conflict-free
        float zp = fmaf(q.x, w0[0], fmaf(q.y, w1[0], g.x));
        float fp = fmaf(q.x, w0[1], fmaf(q.y, w1[1], g.y));
        float op = fmaf(q.x, w0[2], fmaf(q.y, w1[2], g.z));
        const float f = sigm(fp);
        const float o = sigm(op);
        const float z = fmaf(2.f, sigm(2.f*zp), -1.f);   // tanh
        c = fmaf(f, c - z, z);
        const float hv = fmaxf(o * c, 0.f);
        *hb = __float2bfloat16(hv);
        hb += stride; t += tstep;
    }
}

// ---------------------------------------------------------------------------
// K2: s[b,t] = dot(hbuf[b,t,:], Mu). One wave per row, 16 bf16/lane via short8.
// ---------------------------------------------------------------------------
__global__ __launch_bounds__(256) void score2(
    const __hip_bfloat16* __restrict__ hbuf, const float* __restrict__ Mu,
    float* __restrict__ s)
{
    const int row  = blockIdx.x*4 + (threadIdx.x >> 6);
    const int lane = threadIdx.x & 63;
    const short8* hp = (const short8*)(hbuf + (size_t)row*DH_);
    const float4* mp = (const float4*)Mu;
    float acc = 0.f;
#pragma unroll
    for (int k = 0; k < 2; ++k) {
        const int idx = k*64 + lane;
        const short8 hv = hp[idx];           // 16B coalesced
        const float4 m0 = mp[idx*2];
        const float4 m1 = mp[idx*2 + 1];
        acc = fmaf(bf2f((unsigned short)hv[0]), m0.x, acc);
        acc = fmaf(bf2f((unsigned short)hv[1]), m0.y, acc);
        acc = fmaf(bf2f((unsigned short)hv[2]), m0.z, acc);
        acc = fmaf(bf2f((unsigned short)hv[3]), m0.w, acc);
        acc = fmaf(bf2f((unsigned short)hv[4]), m1.x, acc);
        acc = fmaf(bf2f((unsigned short)hv[5]), m1.y, acc);
        acc = fmaf(bf2f((unsigned short)hv[6]), m1.z, acc);
        acc = fmaf(bf2f((unsigned short)hv[7]), m1.w, acc);
    }
#pragma unroll
    for (int off = 32; off; off >>= 1) acc += __shfl_down(acc, off);
    if (lane == 0) s[row] = acc;
}

// ---------------------------------------------------------------------------
// K3: softmax over t per batch. grid B, block 512.
// ---------------------------------------------------------------------------
__global__ __launch_bounds__(512) void softmax_kernel(
    const float* __restrict__ s, float* __restrict__ w)
{
    const int b = blockIdx.x;
    const int t = threadIdx.x;
    const float v = s[b*T_ + t];

    __shared__ float redm[8];
    __shared__ float reds[8];

    float m = v;
#pragma unroll
    for (int off = 32; off; off >>= 1) m = fmaxf(m, __shfl_xor(m, off));
    if ((t & 63) == 0) redm[t >> 6] = m;
    __syncthreads();
    float mall = redm[0];
#pragma unroll
    for (int i = 1; i < 8; ++i) mall = fmaxf(mall, redm[i]);

    const float e = __expf(v - mall);
    float sum = e;
#pragma unroll
    for (int off = 32; off; off >>= 1) sum += __shfl_xor(sum, off);
    if ((t & 63) == 0) reds[t >> 6] = sum;
    __syncthreads();
    float sall = 0.f;
#pragma unroll
    for (int i = 0; i < 8; ++i) sall += reds[i];

    w[b*T_ + t] = e / sall;
}

// ---------------------------------------------------------------------------
// K4: context[b,d] = relu(sum_t h[b,t,d] * w[b,t]). Thread owns 2 d's (4B/lane).
// grid (B,2), block 256.
// ---------------------------------------------------------------------------
__global__ __launch_bounds__(256) void context2(
    const __hip_bfloat16* __restrict__ hbuf, const float* __restrict__ w,
    float* __restrict__ ctx)
{
    const int b  = blockIdx.x;
    const int d0 = (blockIdx.y*256 + threadIdx.x)*2;

    __shared__ float ws[T_];
    for (int t = threadIdx.x; t < T_; t += 256) ws[t] = w[b*T_ + t];
    __syncthreads();

    const unsigned int* hp = (const unsigned int*)(hbuf + (size_t)b*T_*DH_ + d0);
    float a0 = 0.f, a1 = 0.f;
#pragma unroll 8
    for (int t = 0; t < T_; ++t) {
        const unsigned int u = hp[(size_t)t*(DH_/2)];
        a0 = fmaf(bf2f((unsigned short)(u & 0xffffu)), ws[t], a0);
        a1 = fmaf(bf2f((unsigned short)(u >> 16)),     ws[t], a1);
    }
    float2* cp = (float2*)(ctx + b*DH_ + d0);
    *cp = make_float2(fmaxf(a0, 0.f), fmaxf(a1, 0.f));
}

// ---------------------------------------------------------------------------
// K5: out[b,o] = dot(ctx[b,:], W_out[o,:]) + b_out[o]. One wave per (b,o).
// ---------------------------------------------------------------------------
__global__ __launch_bounds__(256) void out_kernel(
    const float* __restrict__ ctx, const float* __restrict__ Wout,
    const float* __restrict__ bout, float* __restrict__ out)
{
    const int idx  = blockIdx.x*4 + (threadIdx.x >> 6);  // b*64 + o
    const int lane = threadIdx.x & 63;
    const int b = idx >> 6;
    const int o = idx & 63;
    const float* cp = ctx + b*DH_;
    const float* wp = Wout + o*DH_;
    float acc = 0.f;
#pragma unroll
    for (int k = 0; k < DH_/64; ++k) {
        const int d = lane + k*64;
        acc = fmaf(cp[d], wp[d], acc);
    }
#pragma unroll
    for (int off = 32; off; off >>= 1) acc += __shfl_down(acc, off);
    if (lane == 0) out[idx] = acc + bout[o];
}

// ---------------------------------------------------------------------------
extern "C" void kernel_launch(void* const* d_in, const int* in_sizes, int n_in,
                              void* d_out, int out_size, void* d_ws, size_t ws_size,
                              hipStream_t stream)
{
    const float* x    = (const float*)d_in[0];
    const float* emb  = (const float*)d_in[1];
    const float* Wf   = (const float*)d_in[2];
    const float* bf_  = (const float*)d_in[3];
    const float* Wb   = (const float*)d_in[4];
    const float* bb_  = (const float*)d_in[5];
    const float* Mu   = (const float*)d_in[6];
    const float* Wout = (const float*)d_in[7];
    const float* bout = (const float*)d_in[8];
    float* out = (float*)d_out;

    char* ws = (char*)d_ws;
    const size_t hbytes = (size_t)B_*T_*DH_*sizeof(__hip_bfloat16);  // 128 MB
    __hip_bfloat16* hbuf = (__hip_bfloat16*)ws;
    float* s   = (float*)(ws + hbytes);
    float* w   = s + B_*T_;
    float* ctx = w + B_*T_;

    // scan uses 139 KB dynamic LDS (>64 KB default) — raise the cap every call
    (void)hipFuncSetAttribute((const void*)qrnn_scan2,
                              hipFuncAttributeMaxDynamicSharedMemorySize,
                              SCAN_LDS);

    qrnn_scan2<<<dim3(B_, 2), 512, SCAN_LDS, stream>>>(x, emb, Wf, bf_, Wb, bb_, hbuf);
    score2<<<(B_*T_)/4, 256, 0, stream>>>(hbuf, Mu, s);
    softmax_kernel<<<B_, 512, 0, stream>>>(s, w);
    context2<<<dim3(B_, 2), 256, 0, stream>>>(hbuf, w, ctx);
    out_kernel<<<(B_*OUT_)/4, 256, 0, stream>>>(ctx, Wout, bout, out);
}